// Round 19
// baseline (99.690 us; speedup 1.0000x reference)
//
#include <hip/hip_runtime.h>

// MemoryEfficientAttention: B=2,H=16,S=4096,D=128, CHUNK=1024.
// R19 = R15 scaled to 1024-thr blocks: wave = (chunk, quarter h), block =
// one 128-row q-tile. 16 waves/block = 4 waves/SIMD (2x latency hiding),
// each staged tile serves 512 q-rows, wall = 8 phases (qt=7 blocks).
// Grid 256 = 32 bh x 8 qt = exactly 1 block/CU. KBLK=128, LDS 128KB
// (K,V dbuf), fragment-major layouts (imm ds offsets), no-max softmax,
// gdiag = h diag logic, gll16 DMA.

typedef __attribute__((ext_vector_type(8))) short bfrag_t;   // 8 bf16
typedef __attribute__((ext_vector_type(16))) float f32x16;
typedef unsigned short u16;
typedef unsigned int   u32;

#define SEQ     4096
#define SCHUNK  1024
#define HD      128
#define NT2     8            // 128-row K-tiles per chunk
#define TILE_E2 16384        // elems per staged 128x128 tile

__device__ __forceinline__ u16 f2bf(float f) {
    union { float f; unsigned u; } x; x.f = f;
    unsigned r = x.u + 0x7fffu + ((x.u >> 16) & 1u);   // RNE
    return (u16)(r >> 16);
}

// ---------------- prep: f32 -> bf16 into fragment-major 128-row tiles ----
// K tile: elem K[j][s*8+e] at (s*128 + j)*8 + e        (s=0..15, j=0..127)
// V tile: elem V[sv*8+jj][d] at (sv*128 + d)*8 + jj    (sv=0..15, d=0..127)
__global__ __launch_bounds__(256)
void mea_prep(const float* __restrict__ kg, const float* __restrict__ vg,
              u16* __restrict__ wsK, u16* __restrict__ wsV)
{
    const int tid  = threadIdx.x;
    const int tile = blockIdx.x;            // 256 = 32 bh x 8 kt
    const int bh = tile >> 3, kt = tile & 7;
    const long gsrc = (long)bh * SEQ * HD + (long)kt * 128 * HD;
    const long gdst = (long)tile * TILE_E2;

#pragma unroll
    for (int i = 0; i < 8; ++i) {
        int oid = i * 256 + tid;            // 2048 granules of 8 elems
        int s = oid >> 7, j = oid & 127;
        const float* kp = kg + gsrc + j * HD + s * 8;
        float4 a = *(const float4*)kp;
        float4 b = *(const float4*)(kp + 4);
        bfrag_t f;
        f[0]=f2bf(a.x); f[1]=f2bf(a.y); f[2]=f2bf(a.z); f[3]=f2bf(a.w);
        f[4]=f2bf(b.x); f[5]=f2bf(b.y); f[6]=f2bf(b.z); f[7]=f2bf(b.w);
        *(bfrag_t*)(wsK + gdst + (s * 128 + j) * 8) = f;
    }
#pragma unroll
    for (int i = 0; i < 8; ++i) {
        int oid = i * 256 + tid;
        int sv = oid >> 7, d = oid & 127;
        const float* vp = vg + gsrc + sv * 8 * HD + d;
        bfrag_t f;
#pragma unroll
        for (int jj = 0; jj < 8; ++jj) f[jj] = f2bf(vp[jj * HD]);
        *(bfrag_t*)(wsV + gdst + (sv * 128 + d) * 8) = f;
    }
}

__device__ __forceinline__ void gll16(const u16* g, u16* l) {
    __builtin_amdgcn_global_load_lds((const __attribute__((address_space(1))) u32*)g,
                                     (__attribute__((address_space(3))) u32*)l, 16, 0, 0);
}

__device__ __forceinline__ float tsum16(const f32x16& p) {
    float a0 = (p[0] + p[1]) + (p[2] + p[3]);
    float a1 = (p[4] + p[5]) + (p[6] + p[7]);
    float a2 = (p[8] + p[9]) + (p[10] + p[11]);
    float a3 = (p[12] + p[13]) + (p[14] + p[15]);
    return (a0 + a1) + (a2 + a3);
}

// exp2 in place, accumulate row-sum, pack to two PV A-fragments
__device__ __forceinline__ void sm_cvt(f32x16& s, float& lsum, bfrag_t* pf) {
#pragma unroll
    for (int r = 0; r < 16; ++r) s[r] = exp2f(s[r]);
    lsum += tsum16(s);
    u32 W[8];
#pragma unroll
    for (int t2 = 0; t2 < 8; ++t2)
        asm("v_cvt_pk_bf16_f32 %0, %1, %2"
            : "=v"(W[t2]) : "v"(s[2 * t2]), "v"(s[2 * t2 + 1]));
#pragma unroll
    for (int u2 = 0; u2 < 2; ++u2) {
        u32 x0 = W[4 * u2 + 0], y0 = W[4 * u2 + 2];
        u32 x1 = W[4 * u2 + 1], y1 = W[4 * u2 + 3];
        asm("v_permlane32_swap_b32 %0, %1" : "+v"(x0), "+v"(y0));
        asm("v_permlane32_swap_b32 %0, %1" : "+v"(x1), "+v"(y1));
        union { u32 w[4]; bfrag_t f; } cvt;
        cvt.w[0] = x0; cvt.w[1] = x1; cvt.w[2] = y0; cvt.w[3] = y1;
        pf[u2] = cvt.f;
    }
}

// ---------------- main attention kernel ----------------
__global__ __launch_bounds__(1024, 4)
void mea_main(const float* __restrict__ qg, const u16* __restrict__ wsK,
              const u16* __restrict__ wsV, float* __restrict__ og)
{
    __shared__ __align__(16) u16 K_s[2][TILE_E2];   // 32KB x2
    __shared__ __align__(16) u16 V_s[2][TILE_E2];   // 32KB x2

    const int tid  = threadIdx.x;
    const int lane = tid & 63;
    const int wv   = tid >> 6;       // 0..15: chunk = wv&3, quarter h = wv>>2
    const int c31  = lane & 31;
    const int hi   = lane >> 5;
    const int ch   = wv & 3;
    const int h    = wv >> 2;        // 0..3

    // 256 blocks = 1/CU: 4 bh per XCD, 8 q-tiles per bh, heavy qt first.
    const int x   = blockIdx.x & 7;
    const int idx = blockIdx.x >> 3;          // 0..31
    const int bh  = x * 4 + (idx & 3);
    const int qt  = 7 - (idx >> 2);           // 128-row q-tile, heavy first

    const long rowbase = (long)bh * SEQ + (long)ch * SCHUNK
                       + (long)qt * 128 + (long)h * 32;   // wave's first q-row
    const u16* Kb = wsK + (long)bh * NT2 * TILE_E2;
    const u16* Vb = wsV + (long)bh * NT2 * TILE_E2;
    const int so   = wv * 1024 + lane * 8;    // wave's 2KB slice of each tile
    const int ldsb = wv * 1024;               // wave-uniform LDS dest base
    const float qs = 0.12751723f;             // rsqrt(128) * log2(e)

    // loop-invariant per-lane fragment bases; per-access offsets are imms
    const int kfo = hi * 1024 + c31 * 8;
    const int vfo = hi * 1024 + c31 * 8;

    const int nt = qt + 1;                    // 128-row K-tile count

    // ---- Q fragments (B-op: n=q=c31, k=d=ks*16+hi*8+e); fold scale*log2e
    bfrag_t qf[8];
    {
        const float* qp = qg + (rowbase + c31) * HD + hi * 8;
#pragma unroll
        for (int ks = 0; ks < 8; ++ks) {
            float4 a = *(const float4*)(qp + ks * 16);
            float4 b = *(const float4*)(qp + ks * 16 + 4);
            bfrag_t f;
            f[0]=f2bf(a.x*qs); f[1]=f2bf(a.y*qs); f[2]=f2bf(a.z*qs); f[3]=f2bf(a.w*qs);
            f[4]=f2bf(b.x*qs); f[5]=f2bf(b.y*qs); f[6]=f2bf(b.z*qs); f[7]=f2bf(b.w*qs);
            qf[ks] = f;
        }
    }

    f32x16 oacc[4];
#pragma unroll
    for (int d = 0; d < 4; ++d)
#pragma unroll
        for (int i = 0; i < 16; ++i) oacc[d][i] = 0.f;
    float lsum = 0.f;

    // prologue: DMA K(0), V(0) -> buf0 (2+2 gll16 per wave)
#pragma unroll
    for (int c = 0; c < 2; ++c) {
        gll16(Kb + so + c * 512, &K_s[0][ldsb + c * 512]);
        gll16(Vb + so + c * 512, &V_s[0][ldsb + c * 512]);
    }

    int cur = 0;
    for (int kt = 0; kt < nt; ++kt) {
        __syncthreads();   // vmcnt(0): K(kt),V(kt) landed everywhere; bufs ^1 free

        if (kt + 1 < nt) {   // prefetch next tile
            const long tb = (long)(kt + 1) * TILE_E2;
#pragma unroll
            for (int c = 0; c < 2; ++c) {
                gll16(Kb + tb + so + c * 512, &K_s[cur ^ 1][ldsb + c * 512]);
                gll16(Vb + tb + so + c * 512, &V_s[cur ^ 1][ldsb + c * 512]);
            }
        }

        // group visibility: last tile -> groups < h full, == h tri-masked,
        // > h skipped (h = wave's q-quarter). Non-last tiles: all 4 full.
        const bool last  = (kt == nt - 1);
        const int  gdiag = last ? h : 4;

        const u16* kbase = &K_s[cur][kfo];
        const u16* vbase = &V_s[cur][vfo];

#pragma unroll
        for (int g = 0; g < 4; ++g) {
            if (g <= gdiag) {
                const bool tri = (g == gdiag);   // only reachable when last
                f32x16 s;
#pragma unroll
                for (int i = 0; i < 16; ++i) s[i] = 0.f;
#pragma unroll
                for (int ks = 0; ks < 8; ++ks) {
                    bfrag_t kf = *(const bfrag_t*)(kbase + ks * 2048 + g * 256);
                    s = __builtin_amdgcn_mfma_f32_32x32x16_bf16(kf, qf[ks], s, 0, 0, 0);
                }
                if (tri) {   // tri-mask: k-row-in-group > q-col
#pragma unroll
                    for (int r = 0; r < 16; ++r) {
                        int crow = (r & 3) + 8 * (r >> 2) + 4 * hi;
                        if (crow > c31) s[r] = -1e30f;
                    }
                }
                bfrag_t pf[2];
                sm_cvt(s, lsum, pf);
#pragma unroll
                for (int dg = 0; dg < 4; ++dg) {
#pragma unroll
                    for (int j2 = 0; j2 < 2; ++j2) {
                        bfrag_t vf = *(const bfrag_t*)(vbase + (g * 2 + j2) * 2048 + dg * 256);
                        oacc[dg] = __builtin_amdgcn_mfma_f32_32x32x16_bf16(vf, pf[j2], oacc[dg], 0, 0, 0);
                    }
                }
            }
        }

        cur ^= 1;
    }

    // ---- epilogue: cross-half lsum, divide, store
    lsum += __shfl_xor(lsum, 32);
    float inv = 1.f / lsum;
#pragma unroll
    for (int dg = 0; dg < 4; ++dg) {
#pragma unroll
        for (int rq = 0; rq < 4; ++rq) {
            float4 v;
            v.x = oacc[dg][rq * 4 + 0] * inv;
            v.y = oacc[dg][rq * 4 + 1] * inv;
            v.z = oacc[dg][rq * 4 + 2] * inv;
            v.w = oacc[dg][rq * 4 + 3] * inv;
            *(float4*)(og + (rowbase + c31) * HD + dg * 32 + rq * 8 + hi * 4) = v;
        }
    }
}

extern "C" void kernel_launch(void* const* d_in, const int* in_sizes, int n_in,
                              void* d_out, int out_size, void* d_ws, size_t ws_size,
                              hipStream_t stream)
{
    (void)in_sizes; (void)n_in; (void)out_size; (void)ws_size;
    const float* q = (const float*)d_in[0];
    const float* k = (const float*)d_in[1];
    const float* v = (const float*)d_in[2];
    float* o = (float*)d_out;
    u16* wsK = (u16*)d_ws;
    u16* wsV = wsK + (size_t)32 * NT2 * TILE_E2;   // 8MB each
    mea_prep<<<dim3(256), dim3(256),  0, stream>>>(k, v, wsK, wsV);
    // grid: 256 blocks x 1024 thr = 1 block/CU, 16 waves = 4/SIMD
    mea_main<<<dim3(256), dim3(1024), 0, stream>>>(q, wsK, wsV, o);
}

// Round 20
// 68.435 us; speedup vs baseline: 1.4567x; 1.4567x over previous
//
#include <hip/hip_runtime.h>

// MemoryEfficientAttention: B=2,H=16,S=4096,D=128, CHUNK=1024.
// R20 = R15 verbatim (best verified: 68.5us). KBLK=128, 9 barrier phases,
// 8-wave blocks (512 thr), complement pairing (9 phases for every p),
// LDS 128KB (K,V 32KB tiles, both dbuf), fragment-major layouts (all
// ds_read offsets immediate), 1 barrier/phase, no-max softmax,
// 32-aligned diag group logic, gll16 DMA, setprio.

typedef __attribute__((ext_vector_type(8))) short bfrag_t;   // 8 bf16
typedef __attribute__((ext_vector_type(16))) float f32x16;
typedef unsigned short u16;
typedef unsigned int   u32;

#define SEQ     4096
#define SCHUNK  1024
#define HD      128
#define NT2     8            // 128-row K-tiles per chunk
#define TILE_E2 16384        // elems per staged 128x128 tile

__device__ __forceinline__ u16 f2bf(float f) {
    union { float f; unsigned u; } x; x.f = f;
    unsigned r = x.u + 0x7fffu + ((x.u >> 16) & 1u);   // RNE
    return (u16)(r >> 16);
}

// ---------------- prep: f32 -> bf16 into fragment-major 128-row tiles ----
// K tile: elem K[j][s*8+e] at (s*128 + j)*8 + e        (s=0..15, j=0..127)
// V tile: elem V[sv*8+jj][d] at (sv*128 + d)*8 + jj    (sv=0..15, d=0..127)
__global__ __launch_bounds__(256)
void mea_prep(const float* __restrict__ kg, const float* __restrict__ vg,
              u16* __restrict__ wsK, u16* __restrict__ wsV)
{
    const int tid  = threadIdx.x;
    const int tile = blockIdx.x;            // 256 = 32 bh x 8 kt
    const int bh = tile >> 3, kt = tile & 7;
    const long gsrc = (long)bh * SEQ * HD + (long)kt * 128 * HD;
    const long gdst = (long)tile * TILE_E2;

#pragma unroll
    for (int i = 0; i < 8; ++i) {
        int oid = i * 256 + tid;            // 2048 granules of 8 elems
        int s = oid >> 7, j = oid & 127;
        const float* kp = kg + gsrc + j * HD + s * 8;
        float4 a = *(const float4*)kp;
        float4 b = *(const float4*)(kp + 4);
        bfrag_t f;
        f[0]=f2bf(a.x); f[1]=f2bf(a.y); f[2]=f2bf(a.z); f[3]=f2bf(a.w);
        f[4]=f2bf(b.x); f[5]=f2bf(b.y); f[6]=f2bf(b.z); f[7]=f2bf(b.w);
        *(bfrag_t*)(wsK + gdst + (s * 128 + j) * 8) = f;
    }
#pragma unroll
    for (int i = 0; i < 8; ++i) {
        int oid = i * 256 + tid;
        int sv = oid >> 7, d = oid & 127;
        const float* vp = vg + gsrc + sv * 8 * HD + d;
        bfrag_t f;
#pragma unroll
        for (int jj = 0; jj < 8; ++jj) f[jj] = f2bf(vp[jj * HD]);
        *(bfrag_t*)(wsV + gdst + (sv * 128 + d) * 8) = f;
    }
}

__device__ __forceinline__ void gll16(const u16* g, u16* l) {
    __builtin_amdgcn_global_load_lds((const __attribute__((address_space(1))) u32*)g,
                                     (__attribute__((address_space(3))) u32*)l, 16, 0, 0);
}

__device__ __forceinline__ float tsum16(const f32x16& p) {
    float a0 = (p[0] + p[1]) + (p[2] + p[3]);
    float a1 = (p[4] + p[5]) + (p[6] + p[7]);
    float a2 = (p[8] + p[9]) + (p[10] + p[11]);
    float a3 = (p[12] + p[13]) + (p[14] + p[15]);
    return (a0 + a1) + (a2 + a3);
}

// exp2 in place, accumulate row-sum, pack to two PV A-fragments
__device__ __forceinline__ void sm_cvt(f32x16& s, float& lsum, bfrag_t* pf) {
#pragma unroll
    for (int r = 0; r < 16; ++r) s[r] = exp2f(s[r]);
    lsum += tsum16(s);
    u32 W[8];
#pragma unroll
    for (int t2 = 0; t2 < 8; ++t2)
        asm("v_cvt_pk_bf16_f32 %0, %1, %2"
            : "=v"(W[t2]) : "v"(s[2 * t2]), "v"(s[2 * t2 + 1]));
#pragma unroll
    for (int u2 = 0; u2 < 2; ++u2) {
        u32 x0 = W[4 * u2 + 0], y0 = W[4 * u2 + 2];
        u32 x1 = W[4 * u2 + 1], y1 = W[4 * u2 + 3];
        asm("v_permlane32_swap_b32 %0, %1" : "+v"(x0), "+v"(y0));
        asm("v_permlane32_swap_b32 %0, %1" : "+v"(x1), "+v"(y1));
        union { u32 w[4]; bfrag_t f; } cvt;
        cvt.w[0] = x0; cvt.w[1] = x1; cvt.w[2] = y0; cvt.w[3] = y1;
        pf[u2] = cvt.f;
    }
}

// ---------------- main attention kernel ----------------
__global__ __launch_bounds__(512, 2)
void mea_main(const float* __restrict__ qg, const u16* __restrict__ wsK,
              const u16* __restrict__ wsV, float* __restrict__ og)
{
    __shared__ __align__(16) u16 K_s[2][TILE_E2];   // 32KB x2
    __shared__ __align__(16) u16 V_s[2][TILE_E2];   // 32KB x2

    const int tid  = threadIdx.x;
    const int lane = tid & 63;
    const int wv   = tid >> 6;       // 0..7: chunk = wv&3, q-half h = wv>>2
    const int c31  = lane & 31;
    const int hi   = lane >> 5;
    const int ch   = wv & 3;
    const int h    = wv >> 2;

    // XCD-aware: 4 bh per XCD; 8 segment-pairs p per bh. 256 blocks = 1/CU.
    const int x   = blockIdx.x & 7;
    const int idx = blockIdx.x >> 3;          // 0..31
    const int bh  = x * 4 + (idx & 3);
    const int p   = idx >> 2;                 // 0..7

    const long bhrow = (long)bh * SEQ + (long)ch * SCHUNK + (long)h * 32;
    const u16* Kb = wsK + (long)bh * NT2 * TILE_E2;
    const u16* Vb = wsV + (long)bh * NT2 * TILE_E2;
    const int so   = wv * 2048 + lane * 8;    // wave's 4KB slice of each tile
    const int ldsb = wv * 2048;               // wave-uniform LDS dest base
    const float qs = 0.12751723f;             // rsqrt(128) * log2(e)

    // loop-invariant per-lane fragment bases; per-access offsets are imms
    const int kfo = hi * 1024 + c31 * 8;
    const int vfo = hi * 1024 + c31 * 8;

    // prologue: DMA K(0), V(0) of segment A -> buf0 (4+4 gll16 per wave)
#pragma unroll
    for (int c = 0; c < 4; ++c) {
        gll16(Kb + so + c * 512, &K_s[0][ldsb + c * 512]);
        gll16(Vb + so + c * 512, &V_s[0][ldsb + c * 512]);
    }

    int cur = 0;
    for (int seg = 0; seg < 2; ++seg) {
        const int qt  = seg ? p : (15 - p);   // 64-row q-tile index
        const int nt2 = (qt >> 1) + 1;        // 128-row K-tile count
        const long rowbase = bhrow + (long)qt * 64;   // this wave's first q-row

        // ---- Q fragments (B-op: n=q=c31, k=d=ks*16+hi*8+e); fold scale*log2e
        bfrag_t qf[8];
        {
            const float* qp = qg + (rowbase + c31) * HD + hi * 8;
#pragma unroll
            for (int ks = 0; ks < 8; ++ks) {
                float4 a = *(const float4*)(qp + ks * 16);
                float4 b = *(const float4*)(qp + ks * 16 + 4);
                bfrag_t f;
                f[0]=f2bf(a.x*qs); f[1]=f2bf(a.y*qs); f[2]=f2bf(a.z*qs); f[3]=f2bf(a.w*qs);
                f[4]=f2bf(b.x*qs); f[5]=f2bf(b.y*qs); f[6]=f2bf(b.z*qs); f[7]=f2bf(b.w*qs);
                qf[ks] = f;
            }
        }

        f32x16 oacc[4];
#pragma unroll
        for (int d = 0; d < 4; ++d)
#pragma unroll
            for (int i = 0; i < 16; ++i) oacc[d][i] = 0.f;
        float lsum = 0.f;

        for (int kt = 0; kt < nt2; ++kt) {
            __syncthreads();   // vmcnt(0): K(kt),V(kt) landed everywhere; bufs ^1 free

            // prefetch next tile of this segment, or segment B's tile 0 at the seam
            if (kt + 1 < nt2) {
                const long tb = (long)(kt + 1) * TILE_E2;
#pragma unroll
                for (int c = 0; c < 4; ++c) {
                    gll16(Kb + tb + so + c * 512, &K_s[cur ^ 1][ldsb + c * 512]);
                    gll16(Vb + tb + so + c * 512, &V_s[cur ^ 1][ldsb + c * 512]);
                }
            } else if (seg == 0) {
#pragma unroll
                for (int c = 0; c < 4; ++c) {
                    gll16(Kb + so + c * 512, &K_s[cur ^ 1][ldsb + c * 512]);
                    gll16(Vb + so + c * 512, &V_s[cur ^ 1][ldsb + c * 512]);
                }
            }

            // group visibility: on the last tile, groups < gdiag full,
            // == gdiag tri-masked, > gdiag skipped. gdiag = h (even qt) / 2+h (odd).
            const bool last  = (kt == nt2 - 1);
            const int  gdiag = last ? ((qt * 64 + h * 32 - kt * 128) >> 5) : 4;

            const u16* kbase = &K_s[cur][kfo];
            const u16* vbase = &V_s[cur][vfo];

#pragma unroll
            for (int g = 0; g < 4; ++g) {
                if (g <= gdiag) {
                    const bool tri = (g == gdiag);   // only possible when last
                    f32x16 s;
#pragma unroll
                    for (int i = 0; i < 16; ++i) s[i] = 0.f;
                    __builtin_amdgcn_s_setprio(1);
#pragma unroll
                    for (int ks = 0; ks < 8; ++ks) {
                        bfrag_t kf = *(const bfrag_t*)(kbase + ks * 2048 + g * 256);
                        s = __builtin_amdgcn_mfma_f32_32x32x16_bf16(kf, qf[ks], s, 0, 0, 0);
                    }
                    __builtin_amdgcn_s_setprio(0);
                    if (tri) {   // tri-mask: k-row-in-group > q-col
#pragma unroll
                        for (int r = 0; r < 16; ++r) {
                            int crow = (r & 3) + 8 * (r >> 2) + 4 * hi;
                            if (crow > c31) s[r] = -1e30f;
                        }
                    }
                    bfrag_t pf[2];
                    sm_cvt(s, lsum, pf);
                    __builtin_amdgcn_s_setprio(1);
#pragma unroll
                    for (int dg = 0; dg < 4; ++dg) {
#pragma unroll
                        for (int j2 = 0; j2 < 2; ++j2) {
                            bfrag_t vf = *(const bfrag_t*)(vbase + (g * 2 + j2) * 2048 + dg * 256);
                            oacc[dg] = __builtin_amdgcn_mfma_f32_32x32x16_bf16(vf, pf[j2], oacc[dg], 0, 0, 0);
                        }
                    }
                    __builtin_amdgcn_s_setprio(0);
                }
            }

            cur ^= 1;
        }

        // ---- per-segment epilogue: cross-half lsum, divide, store
        lsum += __shfl_xor(lsum, 32);
        float inv = 1.f / lsum;
#pragma unroll
        for (int dg = 0; dg < 4; ++dg) {
#pragma unroll
            for (int rq = 0; rq < 4; ++rq) {
                float4 v;
                v.x = oacc[dg][rq * 4 + 0] * inv;
                v.y = oacc[dg][rq * 4 + 1] * inv;
                v.z = oacc[dg][rq * 4 + 2] * inv;
                v.w = oacc[dg][rq * 4 + 3] * inv;
                *(float4*)(og + (rowbase + c31) * HD + dg * 32 + rq * 8 + hi * 4) = v;
            }
        }
    }
}

extern "C" void kernel_launch(void* const* d_in, const int* in_sizes, int n_in,
                              void* d_out, int out_size, void* d_ws, size_t ws_size,
                              hipStream_t stream)
{
    (void)in_sizes; (void)n_in; (void)out_size; (void)ws_size;
    const float* q = (const float*)d_in[0];
    const float* k = (const float*)d_in[1];
    const float* v = (const float*)d_in[2];
    float* o = (float*)d_out;
    u16* wsK = (u16*)d_ws;
    u16* wsV = wsK + (size_t)32 * NT2 * TILE_E2;   // 8MB each
    mea_prep<<<dim3(256), dim3(256), 0, stream>>>(k, v, wsK, wsV);
    // grid: 256 blocks x 512 thr = exactly 1 block/CU; 9 phases per block
    mea_main<<<dim3(256), dim3(512), 0, stream>>>(q, wsK, wsV, o);
}